// Round 9
// baseline (10197.321 us; speedup 1.0000x reference)
//
#include <hip/hip_runtime.h>
#include <math.h>

#define HID   256
#define GATES 1024   // 4*HID
#define BATCH 64
#define SEQ   2048

// ---------------------------------------------------------------------------
// GEMM: out[r][g] = sum_k A_row(r)[k] * W[g][k] + bias[g]   (unchanged)
// ---------------------------------------------------------------------------
#define BM 128
#define BN 128
#define BK 16
#define LDP 132

__global__ __launch_bounds__(256, 2)
void xg_gemm(const float* __restrict__ A, const float* __restrict__ W,
             const float* __restrict__ bias, float* __restrict__ out,
             int a_bstride, int ch_log2)
{
    __shared__ float As[BK][LDP];
    __shared__ float Ws[BK][LDP];

    const int tid   = threadIdx.x;
    const int m_blk = blockIdx.x * BM;
    const int n_blk = blockIdx.y * BN;

    const int tn = (tid & 15) * 4;
    const int tm = (tid >> 4) * 4;

    float acc[8][8];
    #pragma unroll
    for (int i = 0; i < 8; ++i)
        #pragma unroll
        for (int j = 0; j < 8; ++j) acc[i][j] = 0.f;

    const int lrow = tid >> 2;
    const int lkc  = (tid & 3) * 4;
    const int CHm1 = (1 << ch_log2) - 1;

    for (int k0 = 0; k0 < HID; k0 += BK) {
        #pragma unroll
        for (int p = 0; p < 2; ++p) {
            int row = p * 64 + lrow;
            int r   = m_blk + row;
            int b   = r >> ch_log2;
            int t   = r & CHm1;
            const float4 a = *(const float4*)(A + (size_t)b * a_bstride +
                                              (size_t)t * HID + k0 + lkc);
            As[lkc + 0][row] = a.x;
            As[lkc + 1][row] = a.y;
            As[lkc + 2][row] = a.z;
            As[lkc + 3][row] = a.w;

            int g = n_blk + row;
            const float4 w = *(const float4*)(W + (size_t)g * HID + k0 + lkc);
            Ws[lkc + 0][row] = w.x;
            Ws[lkc + 1][row] = w.y;
            Ws[lkc + 2][row] = w.z;
            Ws[lkc + 3][row] = w.w;
        }
        __syncthreads();

        #pragma unroll
        for (int kk = 0; kk < BK; ++kk) {
            float4 a0 = *(const float4*)&As[kk][tm];
            float4 a1 = *(const float4*)&As[kk][tm + 64];
            float4 b0 = *(const float4*)&Ws[kk][tn];
            float4 b1 = *(const float4*)&Ws[kk][tn + 64];
            float av[8] = {a0.x, a0.y, a0.z, a0.w, a1.x, a1.y, a1.z, a1.w};
            float bv[8] = {b0.x, b0.y, b0.z, b0.w, b1.x, b1.y, b1.z, b1.w};
            #pragma unroll
            for (int i = 0; i < 8; ++i)
                #pragma unroll
                for (int j = 0; j < 8; ++j)
                    acc[i][j] += av[i] * bv[j];
        }
        __syncthreads();
    }

    const float4 bias0 = *(const float4*)&bias[n_blk + tn];
    const float4 bias1 = *(const float4*)&bias[n_blk + tn + 64];
    #pragma unroll
    for (int i = 0; i < 8; ++i) {
        int m  = (i < 4) ? (tm + i) : (tm + 60 + i);
        int gm = m_blk + m;
        float* op = out + (size_t)gm * GATES + n_blk;
        float4 v0 = {acc[i][0] + bias0.x, acc[i][1] + bias0.y,
                     acc[i][2] + bias0.z, acc[i][3] + bias0.w};
        float4 v1 = {acc[i][4] + bias1.x, acc[i][5] + bias1.y,
                     acc[i][6] + bias1.z, acc[i][7] + bias1.w};
        *(float4*)(op + tn)      = v0;
        *(float4*)(op + tn + 64) = v1;
    }
}

// ---------------------------------------------------------------------------
// Cooperative recurrence v8: shfl-reduced, ONE barrier, zero LDS conflicts.
// 256 wgs (slice s=0..3, batch b), 1024 threads, 1 wg/CU.
// Thread (u=tid>>4, kc=tid&15) owns gates i,f,g,o of unit u over k-range
// [16kc,16kc+16): 64 weight floats in regs (laundered). The 16 partials of a
// unit live in 16 CONTIGUOUS lanes of one wave -> cross-kc reduction is 4
// __shfl_xor steps per gate (no LDS, no barrier). Owner = lane kc==0 does
// activations + c-update + mailbox publish in-lane.
// LDS per step: h staging only, padded layout hsh[chunk*20+off] ->
// ds_read_b128 addrs are 2-way (kc vs kc+8) + 4-lane broadcast = FREE (m136).
// R8's part[16][260] was 8-way conflicted on write AND reduce-read
// (SQ_LDS_BANK_CONFLICT=524288/dispatch = 2048 cyc/step) - that was the floor.
// ---------------------------------------------------------------------------
#define MBSTRIDE ((size_t)BATCH * HID)   // ulongs per parity block

__device__ __forceinline__ float sigmoid_f(float x) {
    return 1.f / (1.f + __expf(-x));
}
__device__ __forceinline__ float tanh_f(float x) {
    return 1.f - 2.f / (1.f + __expf(2.f * x));
}

__global__ __launch_bounds__(1024, 4)
void lstm_rec_coop(const float* __restrict__ xg, const float* __restrict__ w_hh,
                   const float* __restrict__ b_hh, unsigned long long* mbox,
                   float* __restrict__ c_state, float* __restrict__ h_out,
                   int CH, int gbase)
{
    // h(t-1), parity-buffered; chunk kc at offset kc*20 (pad 4 -> 2-way banks)
    __shared__ __attribute__((aligned(16))) float hsh[2][16 * 20];

    const int s   = blockIdx.x >> 6;
    const int b   = blockIdx.x & 63;
    const int tid = threadIdx.x;
    const int kc  = tid & 15;            // k-chunk
    const int u   = tid >> 4;            // unit 0..63

    // ---- one-time: 4 gate-rows x 16 weights into registers, laundered ----
    float4 wreg[4][4];
    #pragma unroll
    for (int j = 0; j < 4; ++j) {
        const float* wr = w_hh + (size_t)(j * 256 + s * 64 + u) * HID + kc * 16;
        #pragma unroll
        for (int i = 0; i < 4; ++i) {
            float4 w = *(const float4*)(wr + 4 * i);
            asm volatile("" : "+v"(w.x), "+v"(w.y), "+v"(w.z), "+v"(w.w));
            wreg[j][i] = w;
        }
    }

    // ---- one-time: owner-lane (kc==0) unit state & biases ----
    const int gu = s * 64 + u;
    float c_u = 0.f;
    float bh[4] = {0.f, 0.f, 0.f, 0.f};
    if (kc == 0) {
        c_u = c_state[b * HID + gu];
        #pragma unroll
        for (int g = 0; g < 4; ++g) bh[g] = b_hh[g * 256 + gu];
    }

    const float* xg_b = xg + (size_t)b * CH * GATES;

    for (int t = 0; t < CH; ++t) {
        const int gt = gbase + t;
        const int pr = gt & 1;

        // ---- owners: prefetch xg before the spin (latency hides under it) --
        float xv[4];
        if (kc == 0) {
            const float* xp = xg_b + (size_t)t * GATES;
            #pragma unroll
            for (int g = 0; g < 4; ++g) xv[g] = xp[g * 256 + gu];
        }

        // ---- pollers (tid<256): wait for tag, stage h(t-1) into parity LDS -
        if (tid < HID) {
            const unsigned long long* slot =
                mbox + (size_t)pr * MBSTRIDE + b * HID + tid;
            unsigned long long w;
            do {
                w = __hip_atomic_load(slot, __ATOMIC_RELAXED,
                                      __HIP_MEMORY_SCOPE_AGENT);
            } while ((unsigned)(w >> 32) != (unsigned)gt);
            hsh[pr][(tid >> 4) * 20 + (tid & 15)] = __uint_as_float((unsigned)w);
        }
        __syncthreads();   // the ONLY barrier in the step

        // ---- matvec: 16 h floats (2-way/broadcast LDS), 4 gate rows ----
        float pv[4];
        {
            const float4* hq = (const float4*)&hsh[pr][kc * 20];
            float4 h0 = hq[0], h1 = hq[1], h2 = hq[2], h3 = hq[3];
            #pragma unroll
            for (int j = 0; j < 4; ++j) {
                float a = wreg[j][0].x * h0.x + wreg[j][0].y * h0.y
                        + wreg[j][0].z * h0.z + wreg[j][0].w * h0.w;
                a += wreg[j][1].x * h1.x + wreg[j][1].y * h1.y
                   + wreg[j][1].z * h1.z + wreg[j][1].w * h1.w;
                a += wreg[j][2].x * h2.x + wreg[j][2].y * h2.y
                   + wreg[j][2].z * h2.z + wreg[j][2].w * h2.w;
                a += wreg[j][3].x * h3.x + wreg[j][3].y * h3.y
                   + wreg[j][3].z * h3.z + wreg[j][3].w * h3.w;
                pv[j] = a;
            }
        }

        // ---- cross-kc reduce: butterfly over the 16-lane group, no LDS ----
        #pragma unroll
        for (int j = 0; j < 4; ++j) {
            float v = pv[j];
            v += __shfl_xor(v, 1, 64);
            v += __shfl_xor(v, 2, 64);
            v += __shfl_xor(v, 4, 64);
            v += __shfl_xor(v, 8, 64);
            pv[j] = v;
        }

        // ---- owner lane: cell update + publish ----
        if (kc == 0) {
            float ig = sigmoid_f(pv[0] + xv[0] + bh[0]);
            float fg = sigmoid_f(pv[1] + xv[1] + bh[1]);
            float gv = tanh_f   (pv[2] + xv[2] + bh[2]);
            float og = sigmoid_f(pv[3] + xv[3] + bh[3]);
            c_u = fg * c_u + ig * gv;
            float h = og * tanh_f(c_u);

            __hip_atomic_store(
                mbox + (size_t)((gt + 1) & 1) * MBSTRIDE + b * HID + gu,
                ((unsigned long long)(unsigned)(gt + 1) << 32) |
                    (unsigned long long)__float_as_uint(h),
                __ATOMIC_RELAXED, __HIP_MEMORY_SCOPE_AGENT);

            if (h_out) h_out[((size_t)b * CH + t) * HID + gu] = h;
        }
        // stage(t+2) into this parity happens only after every wave here has
        // published (t+1) (each wave holds 4 owner lanes), which happens only
        // after that wave's matvec reads of hsh[pr] completed -> race-free
        // with a single barrier.
    }

    if (kc == 0) c_state[b * HID + gu] = c_u;
}

// ---------------------------------------------------------------------------
__global__ void final_linear(const unsigned long long* __restrict__ hw,
                             const float* __restrict__ w_lin,
                             const float* __restrict__ b_lin,
                             float* __restrict__ out)
{
    int b = blockIdx.x;
    int l = threadIdx.x;
    float p = 0.f;
    #pragma unroll
    for (int j = 0; j < 4; ++j) {
        int u = l + j * 64;
        p += __uint_as_float((unsigned)hw[b * HID + u]) * w_lin[u];
    }
    #pragma unroll
    for (int off = 32; off > 0; off >>= 1) p += __shfl_down(p, off, 64);
    if (l == 0) out[b] = p + b_lin[0];
}

// ---------------------------------------------------------------------------
extern "C" void kernel_launch(void* const* d_in, const int* in_sizes, int n_in,
                              void* d_out, int out_size, void* d_ws, size_t ws_size,
                              hipStream_t stream)
{
    const float* input = (const float*)d_in[0];
    const float* w_ih  = (const float*)d_in[1];
    const float* w_hh  = (const float*)d_in[2];
    const float* b_ih  = (const float*)d_in[3];
    const float* b_hh  = (const float*)d_in[4];
    const float* w_lin = (const float*)d_in[5];
    const float* b_lin = (const float*)d_in[6];
    float* out = (float*)d_out;

    const size_t c_elems  = (size_t)BATCH * HID;
    const size_t mb_bytes = 2 * MBSTRIDE * sizeof(unsigned long long);
    char*  ws   = (char*)d_ws;
    float* c1st = (float*)ws;
    float* c2st = c1st + c_elems;
    unsigned long long* mb1 = (unsigned long long*)(c2st + c_elems);
    unsigned long long* mb2 = mb1 + 2 * MBSTRIDE;
    const size_t zero_bytes = 2 * c_elems * 4 + 2 * mb_bytes;
    float* big  = (float*)(ws + ((zero_bytes + 255) & ~(size_t)255));

    int CH = 256;   // fit-checked; falls back if ws_size is smaller
    while (CH > 16) {
        size_t need = ((zero_bytes + 255) & ~(size_t)255)
                    + ((size_t)2 * BATCH * CH * GATES + (size_t)BATCH * CH * HID) * 4;
        if (need <= ws_size) break;
        CH >>= 1;
    }
    const int ch_log2 = __builtin_ctz((unsigned)CH);

    float* xg1  = big;
    float* xg2  = xg1 + (size_t)BATCH * CH * GATES;
    float* h1ch = xg2 + (size_t)BATCH * CH * GATES;

    hipMemsetAsync(ws, 0, zero_bytes, stream);

    const int NC = SEQ / CH;
    dim3 gblk(BATCH * CH / BM, GATES / BN);

    for (int c = 0; c < NC; ++c) {
        xg_gemm<<<gblk, 256, 0, stream>>>(input + (size_t)c * CH * HID, w_ih,
                                          b_ih, xg1, SEQ * HID, ch_log2);
        lstm_rec_coop<<<256, 1024, 0, stream>>>(xg1, w_hh, b_hh, mb1,
                                                c1st, h1ch, CH, c * CH);
        xg_gemm<<<gblk, 256, 0, stream>>>(h1ch, w_ih + GATES * HID,
                                          b_ih + GATES, xg2, CH * HID, ch_log2);
        lstm_rec_coop<<<256, 1024, 0, stream>>>(xg2, w_hh + (size_t)GATES * HID,
                                                b_hh + GATES, mb2,
                                                c2st, nullptr, CH, c * CH);
    }

    // last h2 (step 2047, tag 2048) sits in mb2 parity-0 block
    final_linear<<<BATCH, 64, 0, stream>>>(mb2, w_lin, b_lin, out);
}

// Round 10
// 7599.577 us; speedup vs baseline: 1.3418x; 1.3418x over previous
//
#include <hip/hip_runtime.h>
#include <math.h>

#define HID   256
#define GATES 1024   // 4*HID
#define BATCH 64
#define SEQ   2048

// ---------------------------------------------------------------------------
// GEMM: out[r][g] = sum_k A_row(r)[k] * W[g][k] + bias[g]   (unchanged)
// ---------------------------------------------------------------------------
#define BM 128
#define BN 128
#define BK 16
#define LDP 132

__global__ __launch_bounds__(256, 2)
void xg_gemm(const float* __restrict__ A, const float* __restrict__ W,
             const float* __restrict__ bias, float* __restrict__ out,
             int a_bstride, int ch_log2)
{
    __shared__ float As[BK][LDP];
    __shared__ float Ws[BK][LDP];

    const int tid   = threadIdx.x;
    const int m_blk = blockIdx.x * BM;
    const int n_blk = blockIdx.y * BN;

    const int tn = (tid & 15) * 4;
    const int tm = (tid >> 4) * 4;

    float acc[8][8];
    #pragma unroll
    for (int i = 0; i < 8; ++i)
        #pragma unroll
        for (int j = 0; j < 8; ++j) acc[i][j] = 0.f;

    const int lrow = tid >> 2;
    const int lkc  = (tid & 3) * 4;
    const int CHm1 = (1 << ch_log2) - 1;

    for (int k0 = 0; k0 < HID; k0 += BK) {
        #pragma unroll
        for (int p = 0; p < 2; ++p) {
            int row = p * 64 + lrow;
            int r   = m_blk + row;
            int b   = r >> ch_log2;
            int t   = r & CHm1;
            const float4 a = *(const float4*)(A + (size_t)b * a_bstride +
                                              (size_t)t * HID + k0 + lkc);
            As[lkc + 0][row] = a.x;
            As[lkc + 1][row] = a.y;
            As[lkc + 2][row] = a.z;
            As[lkc + 3][row] = a.w;

            int g = n_blk + row;
            const float4 w = *(const float4*)(W + (size_t)g * HID + k0 + lkc);
            Ws[lkc + 0][row] = w.x;
            Ws[lkc + 1][row] = w.y;
            Ws[lkc + 2][row] = w.z;
            Ws[lkc + 3][row] = w.w;
        }
        __syncthreads();

        #pragma unroll
        for (int kk = 0; kk < BK; ++kk) {
            float4 a0 = *(const float4*)&As[kk][tm];
            float4 a1 = *(const float4*)&As[kk][tm + 64];
            float4 b0 = *(const float4*)&Ws[kk][tn];
            float4 b1 = *(const float4*)&Ws[kk][tn + 64];
            float av[8] = {a0.x, a0.y, a0.z, a0.w, a1.x, a1.y, a1.z, a1.w};
            float bv[8] = {b0.x, b0.y, b0.z, b0.w, b1.x, b1.y, b1.z, b1.w};
            #pragma unroll
            for (int i = 0; i < 8; ++i)
                #pragma unroll
                for (int j = 0; j < 8; ++j)
                    acc[i][j] += av[i] * bv[j];
        }
        __syncthreads();
    }

    const float4 bias0 = *(const float4*)&bias[n_blk + tn];
    const float4 bias1 = *(const float4*)&bias[n_blk + tn + 64];
    #pragma unroll
    for (int i = 0; i < 8; ++i) {
        int m  = (i < 4) ? (tm + i) : (tm + 60 + i);
        int gm = m_blk + m;
        float* op = out + (size_t)gm * GATES + n_blk;
        float4 v0 = {acc[i][0] + bias0.x, acc[i][1] + bias0.y,
                     acc[i][2] + bias0.z, acc[i][3] + bias0.w};
        float4 v1 = {acc[i][4] + bias1.x, acc[i][5] + bias1.y,
                     acc[i][6] + bias1.z, acc[i][7] + bias1.w};
        *(float4*)(op + tn)      = v0;
        *(float4*)(op + tn + 64) = v1;
    }
}

// ---------------------------------------------------------------------------
// Cooperative recurrence v9: DS-pipe-minimal exchange.
// Model (R7/R8/R9 evidence): step time == total DS-pipe cycles/CU/step.
//   R7: 256 ds_read_b128 ≈ 3072cy; R8: 768 + 8-way-conflicted part (b128,
//   pitch 260) ≈ 3200; R9: 768 + 256 bpermute ≈ 3100 — all ≈ 1.5-2.2 us.
// This version: h-reads 64 b128 (768cy) + part as DENSE [4][64][16] with b32
// writes (banks (16u+kc)%32 = exactly 2-way = FREE, m136; 64 instr ≈ 384cy)
// + owner wave0 reduce 16 b128 uniformly bank-spread (≈192cy). No shfl.
// Total DS ≈ 1.4k cyc -> step ≈ 0.9us predicted.
// Owners: tid<64 (single wave) reduce unit tid, update cell, publish.
// 2 barriers/step; single hsh buffer (stage(t+1) cannot start before B2(t));
// single-atom (tag<<32|h) parity mailbox unchanged (proof in R4-R9).
// ---------------------------------------------------------------------------
#define MBSTRIDE ((size_t)BATCH * HID)   // ulongs per parity block

__device__ __forceinline__ float sigmoid_f(float x) {
    return 1.f / (1.f + __expf(-x));
}
__device__ __forceinline__ float tanh_f(float x) {
    return 1.f - 2.f / (1.f + __expf(2.f * x));
}

__global__ __launch_bounds__(1024, 4)
void lstm_rec_coop(const float* __restrict__ xg, const float* __restrict__ w_hh,
                   const float* __restrict__ b_hh, unsigned long long* mbox,
                   float* __restrict__ c_state, float* __restrict__ h_out,
                   int CH, int gbase)
{
    // h(t-1): chunk kc at offset kc*20 (pad 4 -> read banks 2-way = free)
    __shared__ __attribute__((aligned(16))) float hsh[16 * 20];
    // partials, DENSE: part[gate][unit][kc]; b32 writes 2-way, b128 reads even
    __shared__ __attribute__((aligned(16))) float part[4][64][16];

    const int s   = blockIdx.x >> 6;
    const int b   = blockIdx.x & 63;
    const int tid = threadIdx.x;
    const int kc  = tid & 15;            // k-chunk
    const int u   = tid >> 4;            // unit 0..63

    // ---- one-time: 4 gate-rows x 16 weights into registers, laundered ----
    float4 wreg[4][4];
    #pragma unroll
    for (int j = 0; j < 4; ++j) {
        const float* wr = w_hh + (size_t)(j * 256 + s * 64 + u) * HID + kc * 16;
        #pragma unroll
        for (int i = 0; i < 4; ++i) {
            float4 w = *(const float4*)(wr + 4 * i);
            asm volatile("" : "+v"(w.x), "+v"(w.y), "+v"(w.z), "+v"(w.w));
            wreg[j][i] = w;
        }
    }

    // ---- one-time: owner (tid<64, wave 0) unit state & biases ----
    const int gu = s * 64 + tid;         // valid for tid<64
    float c_u = 0.f;
    float bh[4] = {0.f, 0.f, 0.f, 0.f};
    if (tid < 64) {
        c_u = c_state[b * HID + gu];
        #pragma unroll
        for (int g = 0; g < 4; ++g) bh[g] = b_hh[g * 256 + gu];
    }

    const float* xg_b = xg + (size_t)b * CH * GATES;

    for (int t = 0; t < CH; ++t) {
        const int gt = gbase + t;
        const int pr = gt & 1;

        // ---- owners: prefetch xg before the spin (latency hides under it) --
        float xv[4];
        if (tid < 64) {
            const float* xp = xg_b + (size_t)t * GATES;
            #pragma unroll
            for (int g = 0; g < 4; ++g) xv[g] = xp[g * 256 + gu];
        }

        // ---- pollers (tid<256): wait for tag, stage h(t-1) into LDS ----
        if (tid < HID) {
            const unsigned long long* slot =
                mbox + (size_t)pr * MBSTRIDE + b * HID + tid;
            unsigned long long w;
            do {
                w = __hip_atomic_load(slot, __ATOMIC_RELAXED,
                                      __HIP_MEMORY_SCOPE_AGENT);
            } while ((unsigned)(w >> 32) != (unsigned)gt);
            hsh[(tid >> 4) * 20 + (tid & 15)] = __uint_as_float((unsigned)w);
        }
        __syncthreads();   // B1: hsh ready

        // ---- matvec: 16 h floats (4 b128, 2-way/broadcast), 4 gate rows ----
        {
            const float4* hq = (const float4*)&hsh[kc * 20];
            float4 h0 = hq[0], h1 = hq[1], h2 = hq[2], h3 = hq[3];
            #pragma unroll
            for (int j = 0; j < 4; ++j) {
                float a = wreg[j][0].x * h0.x + wreg[j][0].y * h0.y
                        + wreg[j][0].z * h0.z + wreg[j][0].w * h0.w;
                a += wreg[j][1].x * h1.x + wreg[j][1].y * h1.y
                   + wreg[j][1].z * h1.z + wreg[j][1].w * h1.w;
                a += wreg[j][2].x * h2.x + wreg[j][2].y * h2.y
                   + wreg[j][2].z * h2.z + wreg[j][2].w * h2.w;
                a += wreg[j][3].x * h3.x + wreg[j][3].y * h3.y
                   + wreg[j][3].z * h3.z + wreg[j][3].w * h3.w;
                part[j][u][kc] = a;    // b32, banks (16u+kc)%32 -> 2-way free
            }
        }
        __syncthreads();   // B2: partials ready

        // ---- owner wave: reduce 16 kc-chunks per gate, cell update, publish -
        if (tid < 64) {
            float g4[4];
            #pragma unroll
            for (int j = 0; j < 4; ++j) {
                const float4* pp = (const float4*)&part[j][tid][0];
                float4 p0 = pp[0], p1 = pp[1], p2 = pp[2], p3 = pp[3];
                g4[j] = ((p0.x + p0.y) + (p0.z + p0.w))
                      + ((p1.x + p1.y) + (p1.z + p1.w))
                      + ((p2.x + p2.y) + (p2.z + p2.w))
                      + ((p3.x + p3.y) + (p3.z + p3.w));
            }
            float ig = sigmoid_f(g4[0] + xv[0] + bh[0]);
            float fg = sigmoid_f(g4[1] + xv[1] + bh[1]);
            float gv = tanh_f   (g4[2] + xv[2] + bh[2]);
            float og = sigmoid_f(g4[3] + xv[3] + bh[3]);
            c_u = fg * c_u + ig * gv;
            float h = og * tanh_f(c_u);

            __hip_atomic_store(
                mbox + (size_t)((gt + 1) & 1) * MBSTRIDE + b * HID + gu,
                ((unsigned long long)(unsigned)(gt + 1) << 32) |
                    (unsigned long long)__float_as_uint(h),
                __ATOMIC_RELAXED, __HIP_MEMORY_SCOPE_AGENT);

            if (h_out) h_out[((size_t)b * CH + t) * HID + gu] = h;
        }
        // stage(t+1) (first action of next iter) is safe: every thread passes
        // B1(t+1) only after the owner wave finished its part(t) reads and
        // publish; matvec(t) hsh reads completed before B2(t).
    }

    if (tid < 64) c_state[b * HID + gu] = c_u;
}

// ---------------------------------------------------------------------------
__global__ void final_linear(const unsigned long long* __restrict__ hw,
                             const float* __restrict__ w_lin,
                             const float* __restrict__ b_lin,
                             float* __restrict__ out)
{
    int b = blockIdx.x;
    int l = threadIdx.x;
    float p = 0.f;
    #pragma unroll
    for (int j = 0; j < 4; ++j) {
        int u = l + j * 64;
        p += __uint_as_float((unsigned)hw[b * HID + u]) * w_lin[u];
    }
    #pragma unroll
    for (int off = 32; off > 0; off >>= 1) p += __shfl_down(p, off, 64);
    if (l == 0) out[b] = p + b_lin[0];
}

// ---------------------------------------------------------------------------
extern "C" void kernel_launch(void* const* d_in, const int* in_sizes, int n_in,
                              void* d_out, int out_size, void* d_ws, size_t ws_size,
                              hipStream_t stream)
{
    const float* input = (const float*)d_in[0];
    const float* w_ih  = (const float*)d_in[1];
    const float* w_hh  = (const float*)d_in[2];
    const float* b_ih  = (const float*)d_in[3];
    const float* b_hh  = (const float*)d_in[4];
    const float* w_lin = (const float*)d_in[5];
    const float* b_lin = (const float*)d_in[6];
    float* out = (float*)d_out;

    const size_t c_elems  = (size_t)BATCH * HID;
    const size_t mb_bytes = 2 * MBSTRIDE * sizeof(unsigned long long);
    char*  ws   = (char*)d_ws;
    float* c1st = (float*)ws;
    float* c2st = c1st + c_elems;
    unsigned long long* mb1 = (unsigned long long*)(c2st + c_elems);
    unsigned long long* mb2 = mb1 + 2 * MBSTRIDE;
    const size_t zero_bytes = 2 * c_elems * 4 + 2 * mb_bytes;
    float* big  = (float*)(ws + ((zero_bytes + 255) & ~(size_t)255));

    int CH = 256;   // fit-checked; falls back if ws_size is smaller
    while (CH > 16) {
        size_t need = ((zero_bytes + 255) & ~(size_t)255)
                    + ((size_t)2 * BATCH * CH * GATES + (size_t)BATCH * CH * HID) * 4;
        if (need <= ws_size) break;
        CH >>= 1;
    }
    const int ch_log2 = __builtin_ctz((unsigned)CH);

    float* xg1  = big;
    float* xg2  = xg1 + (size_t)BATCH * CH * GATES;
    float* h1ch = xg2 + (size_t)BATCH * CH * GATES;

    hipMemsetAsync(ws, 0, zero_bytes, stream);

    const int NC = SEQ / CH;
    dim3 gblk(BATCH * CH / BM, GATES / BN);

    for (int c = 0; c < NC; ++c) {
        xg_gemm<<<gblk, 256, 0, stream>>>(input + (size_t)c * CH * HID, w_ih,
                                          b_ih, xg1, SEQ * HID, ch_log2);
        lstm_rec_coop<<<256, 1024, 0, stream>>>(xg1, w_hh, b_hh, mb1,
                                                c1st, h1ch, CH, c * CH);
        xg_gemm<<<gblk, 256, 0, stream>>>(h1ch, w_ih + GATES * HID,
                                          b_ih + GATES, xg2, CH * HID, ch_log2);
        lstm_rec_coop<<<256, 1024, 0, stream>>>(xg2, w_hh + (size_t)GATES * HID,
                                                b_hh + GATES, mb2,
                                                c2st, nullptr, CH, c * CH);
    }

    // last h2 (step 2047, tag 2048) sits in mb2 parity-0 block
    final_linear<<<BATCH, 64, 0, stream>>>(mb2, w_lin, b_lin, out);
}